// Round 16
// baseline (207.900 us; speedup 1.0000x reference)
//
#include <hip/hip_runtime.h>
#include <math.h>

// ---------------------------------------------------------------------------
// DeepONet/GAT, fused pipeline (R16 = R15 + a2pl single-round 32-deep batch
// + preb bin LDS dst-cache):
//   memset: BCUR (tiny)
//   preb  : W2->bf16^T + rank-2 logit coeffs + POOLED zero + bin
//   csr   : per-bucket CSR build (compact, window-local scatter)
//   a1f2  : LOW-RANK GAT1 agg -> h1 = W1^T·sacc -> MFMA -> xl2 + logits2
//   a2pl  : GAT2 agg, 1 node/wave, single 32-deep guarded gather round
//   tail  : counts + branch MLPs + combine + final head
// Buckets: 512 nodes (BSH=9), NB <= 128 (N <= 65536), arena 12288 edges.
// ---------------------------------------------------------------------------

#define BSH 9
#define CHUNK 4096
#define ARENA 12288
#define LOG2E 1.44269504088896f

using short8v = __attribute__((ext_vector_type(8))) short;
using f32x4  = __attribute__((ext_vector_type(4))) float;

__device__ __forceinline__ float leaky02(float x){ return fmaxf(x, 0.2f * x); }
__device__ __forceinline__ float elu1(float x){ return x > 0.f ? x : expm1f(x); }
__device__ __forceinline__ unsigned f2bf(float a){
    unsigned u = __float_as_uint(a);
    return (u + 0x7FFFu + ((u >> 16) & 1u)) >> 16;
}
__device__ __forceinline__ unsigned packbf(float a, float b){ return f2bf(a) | (f2bf(b) << 16); }
__device__ __forceinline__ float bflo(unsigned p){ return __uint_as_float(p << 16); }
__device__ __forceinline__ float bfhi(unsigned p){ return __uint_as_float(p & 0xFFFF0000u); }
__device__ __forceinline__ float bfs(unsigned short s){ return __uint_as_float(((unsigned)s) << 16); }
__device__ __forceinline__ float rlanef(float v, int l){
    return __uint_as_float(__builtin_amdgcn_readlane(__float_as_uint(v), l));
}

__device__ __forceinline__ int wave_incl_scan(int v, int lane){
    #pragma unroll
    for (int d = 1; d < 64; d <<= 1){ int u = __shfl_up(v, (unsigned)d, 64); if (lane >= d) v += u; }
    return v;
}

// W2 transpose + alpha coeffs + POOLED zero + edge binning, grid-split.
__global__ __launch_bounds__(256) void preb_kernel(
    const float* __restrict__ W1b, const float* __restrict__ W1t,
    const float* __restrict__ a1sb, const float* __restrict__ a1st,
    const float* __restrict__ a1db, const float* __restrict__ a1dt,
    const int* __restrict__ eib, const int* __restrict__ eit,
    const float* __restrict__ W2b, const float* __restrict__ W2t,
    int* __restrict__ bcur, unsigned* __restrict__ epair,
    unsigned short* __restrict__ w2T, float* __restrict__ alph,
    float* __restrict__ pooled,
    int N, int E, int NB, int histBlocks){
    int bid = blockIdx.x;
    int tid = threadIdx.x;
    __shared__ int hist[128], gpos[128];
    __shared__ int slots[CHUNK];
    __shared__ unsigned short pk[CHUNK];   // (bucket<<9)|dstlow, 16 bits
    if (bid < 2 * histBlocks){
        // ---- bin: bucket-sort one 4096-edge chunk into fixed arenas ----
        int br = (bid >= histBlocks) ? 1 : 0;
        int cb = bid - br * histBlocks;
        const int* ei = br ? eit : eib;
        int start = cb * CHUNK;
        int cnt = min(CHUNK, E - start);
        for (int i = tid; i < 128; i += 256) hist[i] = 0;
        __syncthreads();
        const int* dstp = ei + E + start;
        const int* srcp = ei + start;
        for (int li = tid; li < cnt; li += 256){
            int d = dstp[li];
            int b = d >> BSH;
            slots[li] = atomicAdd(&hist[b], 1);
            pk[li] = (unsigned short)((b << BSH) | (d & ((1 << BSH) - 1)));
        }
        __syncthreads();
        if (tid < NB){
            int h0 = hist[tid];
            gpos[tid] = (h0 > 0) ? atomicAdd(&bcur[br * NB + tid], h0) : 0;
        }
        __syncthreads();
        unsigned* ep = epair + (size_t)br * NB * ARENA;
        for (int li = tid; li < cnt; li += 256){
            unsigned v = pk[li];
            int b = v >> BSH;
            ep[(size_t)b * ARENA + gpos[b] + slots[li]] =
                ((unsigned)srcp[li] << BSH) | (v & ((1u << BSH) - 1));
        }
        return;
    }
    bid -= 2 * histBlocks;
    if (bid < 2){
        // W2T[c][k] = bf16(W2[k][c]) + alpha coeffs, per branch
        int br = bid;
        const float* W2 = br ? W2t : W2b;
        for (int i = tid; i < 8192; i += 256){
            int c = i >> 7, k = i & 127;
            w2T[br * 8192 + i] = (unsigned short)f2bf(W2[k * 64 + c]);
        }
        if (tid < 64){
            const float* W1  = br ? W1t  : W1b;
            const float* a1s = br ? a1st : a1sb;
            const float* a1d = br ? a1dt : a1db;
            int lane = tid;
            for (int k = 0; k < 8; ++k){
                int sd = k >> 2, h = (k >> 1) & 1, xr = k & 1;
                const float* av = sd ? a1d : a1s;
                float p = W1[xr * 128 + h * 64 + lane] * av[h * 64 + lane];
                #pragma unroll
                for (int m = 32; m >= 1; m >>= 1) p += __shfl_xor(p, m, 64);
                if (lane == 0) alph[br * 8 + k] = LOG2E * p;
            }
        }
    } else {
        for (int i = tid; i < 8192; i += 256) pooled[i] = 0.f;
    }
}

// per-bucket CSR: compact bases from bcur scan, local degrees, scatter src.
__global__ __launch_bounds__(256) void csr_kernel(
    const int* __restrict__ bcur, const unsigned* __restrict__ epair,
    int* __restrict__ rs, int* __restrict__ csr, int N, int E, int NB){
    int bid = blockIdx.x;
    int br = (bid >= NB) ? 1 : 0;
    int b = bid - br * NB;
    __shared__ int base2[128];
    __shared__ int deg[512], st[512];
    int tid = threadIdx.x, lane = tid & 63, wid = tid >> 6;
    if (wid == 0){
        int b0 = (lane < NB) ? bcur[br * NB + lane] : 0;
        int b1 = (64 + lane < NB) ? bcur[br * NB + 64 + lane] : 0;
        int g0 = wave_incl_scan(b0, lane); int gt = __shfl(g0, 63, 64);
        int g1 = wave_incl_scan(b1, lane);
        base2[lane] = g0 - b0; base2[64 + lane] = gt + g1 - b1;
    }
    for (int i = tid; i < 512; i += 256) deg[i] = 0;
    __syncthreads();
    int ebase = base2[b];
    int ecnt = bcur[br * NB + b];
    int n0 = b << BSH;
    int nodes = min(512, N - n0);
    const unsigned* ep = epair + ((size_t)br * NB + b) * ARENA;
    for (int i = tid; i < ecnt; i += 256) atomicAdd(&deg[ep[i] & 511u], 1);
    __syncthreads();
    if (wid == 0){
        int carry = 0;
        #pragma unroll
        for (int c = 0; c < 8; ++c){
            int v = deg[c * 64 + lane];
            int s = wave_incl_scan(v, lane);
            st[c * 64 + lane] = carry + s - v;
            carry += __shfl(s, 63, 64);
        }
    }
    __syncthreads();
    int* rsb = rs + (size_t)br * (N + 1);
    for (int i = tid; i < nodes; i += 256) rsb[n0 + i] = ebase + st[i];
    if (b == NB - 1 && tid == 0) rsb[N] = ebase + ecnt;
    for (int i = tid; i < 512; i += 256) deg[i] = st[i];
    __syncthreads();
    int* csrb = csr + (size_t)br * E + ebase;
    for (int i = tid; i < ecnt; i += 256){
        unsigned p = ep[i];
        int pos = atomicAdd(&deg[p & 511u], 1);
        csrb[pos] = (int)(p >> BSH);
    }
}

// Low-rank GAT1 aggregation (8 lanes/node, logits on-the-fly) + h1
// reconstruction + MFMA + layer-2 logits. Block = 32 nodes, 4 waves.
__global__ __launch_bounds__(256) void a1f2_kernel(
    const float* __restrict__ xB, const float* __restrict__ xT,
    const float* __restrict__ alph,
    const int* __restrict__ csr, const int* __restrict__ rs,
    const float* __restrict__ W1b, const float* __restrict__ W1t,
    const float* __restrict__ b1b, const float* __restrict__ b1t,
    const unsigned short* __restrict__ w2T,
    const float* __restrict__ a2sb, const float* __restrict__ a2st,
    const float* __restrict__ a2db, const float* __restrict__ a2dt,
    unsigned short* __restrict__ xl2h, float* __restrict__ es2, float* __restrict__ ed2,
    int N, int E){
    int bid = blockIdx.x;
    int br = bid & 1;                 // branch parity == XCD parity class
    int n0 = (bid >> 1) << 5;         // 32 nodes per block
    const float* x  = br ? xT : xB;
    const int* cs = csr + (size_t)br * E;
    const int* rsb = rs + (size_t)br * (N + 1);
    const float* W1 = br ? W1t : W1b;
    const float* b1 = br ? b1t : b1b;
    const float* a2s = br ? a2st : a2sb;
    const float* a2d = br ? a2dt : a2db;
    const float* al = alph + br * 8;
    float as0x = al[0], as0y = al[1], as1x = al[2], as1y = al[3];
    float ad0x = al[4], ad0y = al[5], ad1x = al[6], ad1y = al[7];

    __shared__ float sacc[32][6];     // per node: d0, s0x, s0y, d1, s1x, s1y
    __shared__ unsigned hl[32][68];   // h1 tile, packed bf16 pairs, padded
    __shared__ float psa[4][32], pda[4][32];
    int tid = threadIdx.x, lane = tid & 63, w = tid >> 6;
    int g = lane >> 3, sl = lane & 7;
    int row = w * 8 + g;
    int n = n0 + row;
    bool valid = n < N;

    // ---- aggregation: 8 lanes per node, register accumulators ----
    float2 xn = ((const float2*)x)[valid ? n : 0];
    float edv0 = ad0x * xn.x + ad0y * xn.y;      // dst logits (pre-scaled)
    float edv1 = ad1x * xn.x + ad1y * xn.y;
    int beg = 0, end = 0;
    if (valid){ beg = rsb[n]; end = rsb[n + 1]; }
    float d0 = 0.f, s0x = 0.f, s0y = 0.f, d1 = 0.f, s1x = 0.f, s1y = 0.f;
    if (valid && sl == 0){            // self-loop term
        float e0 = as0x * xn.x + as0y * xn.y;
        float e1 = as1x * xn.x + as1y * xn.y;
        float w0 = exp2f(leaky02(e0 + edv0));
        float w1 = exp2f(leaky02(e1 + edv1));
        d0 = w0; s0x = w0 * xn.x; s0y = w0 * xn.y;
        d1 = w1; s1x = w1 * xn.x; s1y = w1 * xn.y;
    }
    for (int j = beg + sl; j < end; j += 8){
        int s = cs[j];
        float2 xv = ((const float2*)x)[s];
        float e0 = as0x * xv.x + as0y * xv.y;
        float e1 = as1x * xv.x + as1y * xv.y;
        float w0 = exp2f(leaky02(e0 + edv0));
        float w1 = exp2f(leaky02(e1 + edv1));
        d0 += w0; s0x += w0 * xv.x; s0y += w0 * xv.y;
        d1 += w1; s1x += w1 * xv.x; s1y += w1 * xv.y;
    }
    #pragma unroll
    for (int m = 1; m < 8; m <<= 1){
        d0  += __shfl_xor(d0, m, 64);
        s0x += __shfl_xor(s0x, m, 64);
        s0y += __shfl_xor(s0y, m, 64);
        d1  += __shfl_xor(d1, m, 64);
        s1x += __shfl_xor(s1x, m, 64);
        s1y += __shfl_xor(s1y, m, 64);
    }
    if (sl == 0){
        sacc[row][0] = d0; sacc[row][1] = s0x; sacc[row][2] = s0y;
        sacc[row][3] = d1; sacc[row][4] = s1x; sacc[row][5] = s1y;
    }
    __syncthreads();

    // ---- reconstruct h1 = elu(W1^T sacc / denom + b1), 8 rows per wave ----
    int h = lane >> 5;
    float2 w0c = ((const float2*)W1)[lane];          // W1[0, 2l..2l+1]
    float2 w1c = ((const float2*)(W1 + 128))[lane];  // W1[1, 2l..2l+1]
    float b1lo = b1[lane * 2], b1hi = b1[lane * 2 + 1];
    #pragma unroll
    for (int nn = 0; nn < 8; ++nn){
        int r2 = w * 8 + nn;
        int nr = n0 + r2;
        float dinv = 1.f / sacc[r2][3 * h];
        float sx = sacc[r2][3 * h + 1], sy = sacc[r2][3 * h + 2];
        float va = (sx * w0c.x + sy * w1c.x) * dinv + b1lo;
        float vb = (sx * w0c.y + sy * w1c.y) * dinv + b1hi;
        hl[r2][lane] = (nr < N) ? packbf(elu1(va), elu1(vb)) : 0u;
    }

    int lr = lane & 15, lq = lane >> 4;
    // B fragments straight from global bf16 W2T (L1-resident 16KB/branch)
    const unsigned short* wtp = w2T + br * 8192 + (w * 16 + lr) * 128 + lq * 8;
    short8v bf0 = *(const short8v*)(wtp);
    short8v bf1 = *(const short8v*)(wtp + 32);
    short8v bf2 = *(const short8v*)(wtp + 64);
    short8v bf3 = *(const short8v*)(wtp + 96);
    float a2sv = a2s[w * 16 + lr];
    float a2dv = a2d[w * 16 + lr];
    __syncthreads();
    // ---- MFMA: 2 row-tiles x this wave's 16-col tile ----
    #pragma unroll
    for (int rt = 0; rt < 2; ++rt){
        int rb = rt << 4;
        f32x4 ac = {0.f, 0.f, 0.f, 0.f};
        ac = __builtin_amdgcn_mfma_f32_16x16x32_bf16(*(const short8v*)&hl[rb + lr][lq * 4], bf0, ac, 0, 0, 0);
        ac = __builtin_amdgcn_mfma_f32_16x16x32_bf16(*(const short8v*)&hl[rb + lr][16 + lq * 4], bf1, ac, 0, 0, 0);
        ac = __builtin_amdgcn_mfma_f32_16x16x32_bf16(*(const short8v*)&hl[rb + lr][32 + lq * 4], bf2, ac, 0, 0, 0);
        ac = __builtin_amdgcn_mfma_f32_16x16x32_bf16(*(const short8v*)&hl[rb + lr][48 + lq * 4], bf3, ac, 0, 0, 0);
        #pragma unroll
        for (int reg = 0; reg < 4; ++reg){
            int r = rb + lq * 4 + reg;
            int nr = n0 + r;
            float v = ac[reg];
            if (nr < N)
                xl2h[((size_t)br * N + nr) * 64 + w * 16 + lr] = (unsigned short)f2bf(v);
            float ps = v * a2sv, pd = v * a2dv;
            ps += __shfl_xor(ps, 1, 64); ps += __shfl_xor(ps, 2, 64);
            ps += __shfl_xor(ps, 4, 64); ps += __shfl_xor(ps, 8, 64);
            pd += __shfl_xor(pd, 1, 64); pd += __shfl_xor(pd, 2, 64);
            pd += __shfl_xor(pd, 4, 64); pd += __shfl_xor(pd, 8, 64);
            if (lr == 0){ psa[w][r] = ps; pda[w][r] = pd; }
        }
    }
    __syncthreads();
    if (tid < 32){
        int nr = n0 + tid;
        if (nr < N)
            es2[(size_t)br * N + nr] = LOG2E * (psa[0][tid] + psa[1][tid] + psa[2][tid] + psa[3][tid]);
    } else if (tid < 64){
        int r = tid - 32;
        int nr = n0 + r;
        if (nr < N)
            ed2[(size_t)br * N + nr] = LOG2E * (pda[0][r] + pda[1][r] + pda[2][r] + pda[3][r]);
    }
}

// Fused GAT2 aggregation + per-graph pooled sums.
// Edge list + weights hoisted to lanes; SINGLE 32-deep guarded gather round
// (uniform guards, static vv indexing), rare 8-deep rounds beyond 32.
__global__ __launch_bounds__(256) void a2pl_kernel(
    const unsigned short* __restrict__ xl2h, const float* __restrict__ es2, const float* __restrict__ ed2,
    const int* __restrict__ csr, const int* __restrict__ rs,
    const float* __restrict__ b2b, const float* __restrict__ b2t,
    const int* __restrict__ batchb, const int* __restrict__ batcht,
    float* __restrict__ pooled, int N, int E){
    int bid = blockIdx.x;
    int br = bid & 1;                 // branch parity == XCD parity class
    int tid = threadIdx.x, lane = tid & 63, w = tid >> 6;
    int n = ((bid >> 1) << 2) + w;
    const unsigned short* xlt = xl2h + (size_t)br * N * 64;
    const float* es = es2 + (size_t)br * N;
    const float* ed = ed2 + (size_t)br * N;
    const int* cs = csr + (size_t)br * E;
    const int* rsb = rs + (size_t)br * (N + 1);
    const float* b2 = br ? b2t : b2b;
    const int* batch = br ? batcht : batchb;
    float hv = 0.f;
    int g = -1;
    if (n < N){
        g = batch[n];
        float edn = ed[n];
        float wself = exp2f(leaky02(es[n] + edn));
        float denom = wself;
        float acc = wself * bfs(xlt[(unsigned)(n * 64) + lane]);
        int beg = rsb[n];
        int end = rsb[n + 1];
        for (int base = beg; base < end; base += 64){
            int cnt = min(64, end - base);
            int myidx = cs[base + min(lane, cnt - 1)];
            float wmine = (lane < cnt) ? exp2f(leaky02(es[myidx] + edn)) : 0.f;
            float ws = wmine;
            #pragma unroll
            for (int m = 1; m < 64; m <<= 1) ws += __shfl_xor(ws, m, 64);
            denom += ws;
            int cntR = (cnt + 7) & ~7;
            int r1 = min(cntR, 32);
            float vv[32];
            // issue all loads for the first (typically only) round
            #pragma unroll
            for (int blk = 0; blk < 4; ++blk){
                if (blk * 8 < r1){
                    #pragma unroll
                    for (int qq = 0; qq < 8; ++qq){
                        int q = blk * 8 + qq;
                        int s = __builtin_amdgcn_readlane(myidx, q);
                        vv[q] = bfs(xlt[(unsigned)(s * 64) + lane]);
                    }
                }
            }
            // consume
            #pragma unroll
            for (int blk = 0; blk < 4; ++blk){
                if (blk * 8 < r1){
                    #pragma unroll
                    for (int qq = 0; qq < 8; ++qq){
                        int q = blk * 8 + qq;
                        acc += rlanef(wmine, q) * vv[q];
                    }
                }
            }
            // rare edges beyond 32 within this chunk
            for (int q0 = 32; q0 < cntR; q0 += 8){
                float v8[8];
                #pragma unroll
                for (int qq = 0; qq < 8; ++qq){
                    int s = __builtin_amdgcn_readlane(myidx, q0 + qq);
                    v8[qq] = bfs(xlt[(unsigned)(s * 64) + lane]);
                }
                #pragma unroll
                for (int qq = 0; qq < 8; ++qq)
                    acc += rlanef(wmine, q0 + qq) * v8[qq];
            }
        }
        hv = elu1(acc / denom + b2[lane]);
    }
    __shared__ float red[4][64];
    __shared__ int gid[4];
    red[w][lane] = hv;
    if (lane == 0) gid[w] = g;
    __syncthreads();
    if (w == 0){
        int g0 = gid[0], g1 = gid[1], g2 = gid[2], g3 = gid[3];
        float* pb = pooled + (size_t)br * 4096;
        if (g0 >= 0 && g0 == g1 && g1 == g2 && g2 == g3){
            float s = (red[0][lane] + red[1][lane]) + (red[2][lane] + red[3][lane]);
            atomicAdd(&pb[g0 * 64 + lane], s);
        } else {
            #pragma unroll
            for (int q = 0; q < 4; ++q)
                if (gid[q] >= 0) atomicAdd(&pb[gid[q] * 64 + lane], red[q][lane]);
        }
    }
}

// counts (binary search on sorted batch) + branch MLPs + combine + final head
__global__ __launch_bounds__(1024) void tail_kernel(
    const float* __restrict__ pooled,
    const int* __restrict__ batchb, const int* __restrict__ batcht,
    const float* __restrict__ M1wb, const float* __restrict__ M1bb,
    const float* __restrict__ M2wb, const float* __restrict__ M2bb,
    const float* __restrict__ M1wt, const float* __restrict__ M1bt,
    const float* __restrict__ M2wt, const float* __restrict__ M2bt,
    const float* __restrict__ Fw1, const float* __restrict__ Fb1,
    const float* __restrict__ Fw2, const float* __restrict__ Fb2,
    float* __restrict__ out, int N){
    __shared__ float P[8192];
    __shared__ float H[8192];
    __shared__ float cl[128];
    int t = threadIdx.x;
    if (t < 128){
        int br = t >> 6, g = t & 63;
        const int* batch = br ? batcht : batchb;
        int lo = 0, hi = N;
        while (lo < hi){ int mid = (lo + hi) >> 1; if (batch[mid] < g) lo = mid + 1; else hi = mid; }
        int beg = lo;
        hi = N;
        while (lo < hi){ int mid = (lo + hi) >> 1; if (batch[mid] < g + 1) lo = mid + 1; else hi = mid; }
        cl[t] = (float)(lo - beg);
    }
    __syncthreads();
    for (int i = t; i < 8192; i += 1024)
        P[i] = pooled[i] / fmaxf(cl[i >> 6], 1.f);
    __syncthreads();
    for (int i = t; i < 8192; i += 1024){
        int br = i >> 12, r = (i >> 6) & 63, c = i & 63;
        const float* M1w = br ? M1wt : M1wb;
        const float* M1b = br ? M1bt : M1bb;
        float acc = M1b[c];
        int pb = (br << 12) + (r << 6);
        #pragma unroll 8
        for (int k = 0; k < 64; ++k) acc += P[pb + k] * M1w[(k << 6) + c];
        H[i] = fmaxf(acc, 0.f);
    }
    __syncthreads();
    for (int i = t; i < 8192; i += 1024){
        int br = i >> 12, r = (i >> 6) & 63, c = i & 63;
        const float* M2w = br ? M2wt : M2wb;
        const float* M2b = br ? M2bt : M2bb;
        float acc = M2b[c];
        int hb = (br << 12) + (r << 6);
        #pragma unroll 8
        for (int k = 0; k < 64; ++k) acc += H[hb + k] * M2w[(k << 6) + c];
        P[i] = acc;
    }
    __syncthreads();
    for (int i = t; i < 4096; i += 1024) H[i] = P[i] * P[4096 + i];
    __syncthreads();
    for (int i = t; i < 4096; i += 1024){
        int r = i >> 6, c = i & 63;
        float acc = Fb1[c];
        #pragma unroll 8
        for (int k = 0; k < 64; ++k) acc += H[(r << 6) + k] * Fw1[(k << 6) + c];
        P[i] = fmaxf(acc, 0.f);
    }
    __syncthreads();
    if (t < 128){
        int r = t >> 1, jc = t & 1;
        float acc = Fb2[jc];
        #pragma unroll 8
        for (int k = 0; k < 64; ++k) acc += P[(r << 6) + k] * Fw2[k * 2 + jc];
        out[t] = tanhf(acc);
    }
}

extern "C" void kernel_launch(void* const* d_in, const int* in_sizes, int n_in,
                              void* d_out, int out_size, void* d_ws, size_t ws_size,
                              hipStream_t stream){
    const int N = in_sizes[0] / 2;
    const int E = in_sizes[1] / 2;
    const int NB = (N + 511) >> BSH;   // nodes-per-bucket = 512, NB <= 128

    char* ws = (char*)d_ws;
    size_t off = 0;
    auto alloc = [&](size_t bytes) -> char* {
        char* p = ws + off;
        off += (bytes + 255) & ~(size_t)255;
        return p;
    };
    unsigned short* XL2h = (unsigned short*)alloc((size_t)2 * N * 64 * 2);  // EPAIR aliases this
    float* ES2 = (float*)alloc((size_t)2 * N * 4);
    float* ED2 = (float*)alloc((size_t)2 * N * 4);
    int* RS  = (int*)alloc((size_t)2 * (N + 1) * 4);
    int* CSR = (int*)alloc((size_t)2 * E * 4);
    int* BCUR = (int*)alloc((size_t)2 * NB * 4);
    float* POOLED = (float*)alloc(8192 * 4);
    unsigned short* W2T = (unsigned short*)alloc(2 * 8192 * 2);
    float* ALPH = (float*)alloc(16 * 4);
    unsigned* EPAIR = (unsigned*)XL2h;   // 2*NB*ARENA*4 <= 2*N*128 bytes; dead after csr

    const float* xb   = (const float*)d_in[0];
    const int*   eib  = (const int*)  d_in[1];
    const int*   batchb = (const int*)d_in[2];
    const float* W1b  = (const float*)d_in[3];
    const float* a1sb = (const float*)d_in[4];
    const float* a1db = (const float*)d_in[5];
    const float* b1b  = (const float*)d_in[6];
    const float* W2b  = (const float*)d_in[7];
    const float* a2sb = (const float*)d_in[8];
    const float* a2db = (const float*)d_in[9];
    const float* b2b  = (const float*)d_in[10];
    const float* M1wb = (const float*)d_in[11];
    const float* M1bb = (const float*)d_in[12];
    const float* M2wb = (const float*)d_in[13];
    const float* M2bb = (const float*)d_in[14];
    const float* xt   = (const float*)d_in[15];
    const int*   eit  = (const int*)  d_in[16];
    const int*   batcht = (const int*)d_in[17];
    const float* W1t  = (const float*)d_in[18];
    const float* a1st = (const float*)d_in[19];
    const float* a1dt = (const float*)d_in[20];
    const float* b1t  = (const float*)d_in[21];
    const float* W2t  = (const float*)d_in[22];
    const float* a2st = (const float*)d_in[23];
    const float* a2dt = (const float*)d_in[24];
    const float* b2t  = (const float*)d_in[25];
    const float* M1wt = (const float*)d_in[26];
    const float* M1bt = (const float*)d_in[27];
    const float* M2wt = (const float*)d_in[28];
    const float* M2bt = (const float*)d_in[29];
    const float* Fw1  = (const float*)d_in[30];
    const float* Fb1  = (const float*)d_in[31];
    const float* Fw2  = (const float*)d_in[32];
    const float* Fb2  = (const float*)d_in[33];

    const int nodeBlocks = (N + 3) / 4;
    const int histBlocks = (E + CHUNK - 1) / CHUNK;
    const int tilesPer   = (N + 31) / 32;

    hipMemsetAsync(BCUR, 0, (size_t)2 * NB * 4, stream);
    preb_kernel<<<2 * histBlocks + 3, 256, 0, stream>>>(
        W1b, W1t, a1sb, a1st, a1db, a1dt, eib, eit, W2b, W2t,
        BCUR, EPAIR, W2T, ALPH, POOLED, N, E, NB, histBlocks);
    csr_kernel<<<2 * NB, 256, 0, stream>>>(BCUR, EPAIR, RS, CSR, N, E, NB);
    a1f2_kernel<<<2 * tilesPer, 256, 0, stream>>>(
        xb, xt, ALPH, CSR, RS, W1b, W1t, b1b, b1t, W2T,
        a2sb, a2st, a2db, a2dt, XL2h, ES2, ED2, N, E);
    a2pl_kernel<<<2 * nodeBlocks, 256, 0, stream>>>(
        XL2h, ES2, ED2, CSR, RS, b2b, b2t, batchb, batcht, POOLED, N, E);
    tail_kernel<<<1, 1024, 0, stream>>>(POOLED, batchb, batcht,
        M1wb, M1bb, M2wb, M2bb, M1wt, M1bt, M2wt, M2bt,
        Fw1, Fb1, Fw2, Fb2, (float*)d_out, N);
}

// Round 17
// 198.273 us; speedup vs baseline: 1.0486x; 1.0486x over previous
//
#include <hip/hip_runtime.h>
#include <math.h>

// ---------------------------------------------------------------------------
// DeepONet/GAT, fused pipeline (R17 = R15 + a1f2 batched guarded gathers):
//   memset: BCUR (tiny)
//   preb  : W2->bf16^T + rank-2 logit coeffs + POOLED zero + bin
//   csr   : per-bucket CSR build (compact, window-local scatter)
//   a1f2  : LOW-RANK GAT1 agg (4-slot guarded batched gathers, 8 lanes/node)
//           -> h1 = W1^T·sacc -> MFMA -> xl2 + layer-2 logits
//   a2pl  : GAT2 agg (R15 structure: 16-deep + 8-deep rounds, 24 VGPR)
//   tail  : counts + branch MLPs + combine + final head
// Buckets: 512 nodes (BSH=9), NB <= 128 (N <= 65536), arena 12288 edges.
// ---------------------------------------------------------------------------

#define BSH 9
#define CHUNK 4096
#define ARENA 12288
#define LOG2E 1.44269504088896f

using short8v = __attribute__((ext_vector_type(8))) short;
using f32x4  = __attribute__((ext_vector_type(4))) float;

__device__ __forceinline__ float leaky02(float x){ return fmaxf(x, 0.2f * x); }
__device__ __forceinline__ float elu1(float x){ return x > 0.f ? x : expm1f(x); }
__device__ __forceinline__ unsigned f2bf(float a){
    unsigned u = __float_as_uint(a);
    return (u + 0x7FFFu + ((u >> 16) & 1u)) >> 16;
}
__device__ __forceinline__ unsigned packbf(float a, float b){ return f2bf(a) | (f2bf(b) << 16); }
__device__ __forceinline__ float bflo(unsigned p){ return __uint_as_float(p << 16); }
__device__ __forceinline__ float bfhi(unsigned p){ return __uint_as_float(p & 0xFFFF0000u); }
__device__ __forceinline__ float bfs(unsigned short s){ return __uint_as_float(((unsigned)s) << 16); }

__device__ __forceinline__ int wave_incl_scan(int v, int lane){
    #pragma unroll
    for (int d = 1; d < 64; d <<= 1){ int u = __shfl_up(v, (unsigned)d, 64); if (lane >= d) v += u; }
    return v;
}

// W2 transpose + alpha coeffs + POOLED zero + edge binning, grid-split.
__global__ __launch_bounds__(256) void preb_kernel(
    const float* __restrict__ W1b, const float* __restrict__ W1t,
    const float* __restrict__ a1sb, const float* __restrict__ a1st,
    const float* __restrict__ a1db, const float* __restrict__ a1dt,
    const int* __restrict__ eib, const int* __restrict__ eit,
    const float* __restrict__ W2b, const float* __restrict__ W2t,
    int* __restrict__ bcur, unsigned* __restrict__ epair,
    unsigned short* __restrict__ w2T, float* __restrict__ alph,
    float* __restrict__ pooled,
    int N, int E, int NB, int histBlocks){
    int bid = blockIdx.x;
    int tid = threadIdx.x;
    __shared__ int hist[128], gpos[128];
    __shared__ int slots[CHUNK];
    if (bid < 2 * histBlocks){
        // ---- bin: bucket-sort one 4096-edge chunk into fixed arenas ----
        int br = (bid >= histBlocks) ? 1 : 0;
        int cb = bid - br * histBlocks;
        const int* ei = br ? eit : eib;
        int start = cb * CHUNK;
        int cnt = min(CHUNK, E - start);
        for (int i = tid; i < 128; i += 256) hist[i] = 0;
        __syncthreads();
        const int* dstp = ei + E + start;
        const int* srcp = ei + start;
        for (int li = tid; li < cnt; li += 256){
            int b = dstp[li] >> BSH;
            slots[li] = atomicAdd(&hist[b], 1);
        }
        __syncthreads();
        if (tid < NB){
            int h0 = hist[tid];
            gpos[tid] = (h0 > 0) ? atomicAdd(&bcur[br * NB + tid], h0) : 0;
        }
        __syncthreads();
        unsigned* ep = epair + (size_t)br * NB * ARENA;
        for (int li = tid; li < cnt; li += 256){
            int d = dstp[li];
            int b = d >> BSH;
            ep[(size_t)b * ARENA + gpos[b] + slots[li]] =
                ((unsigned)srcp[li] << BSH) | (unsigned)(d & ((1 << BSH) - 1));
        }
        return;
    }
    bid -= 2 * histBlocks;
    if (bid < 2){
        // W2T[c][k] = bf16(W2[k][c]) + alpha coeffs, per branch
        int br = bid;
        const float* W2 = br ? W2t : W2b;
        for (int i = tid; i < 8192; i += 256){
            int c = i >> 7, k = i & 127;
            w2T[br * 8192 + i] = (unsigned short)f2bf(W2[k * 64 + c]);
        }
        if (tid < 64){
            const float* W1  = br ? W1t  : W1b;
            const float* a1s = br ? a1st : a1sb;
            const float* a1d = br ? a1dt : a1db;
            int lane = tid;
            for (int k = 0; k < 8; ++k){
                int sd = k >> 2, h = (k >> 1) & 1, xr = k & 1;
                const float* av = sd ? a1d : a1s;
                float p = W1[xr * 128 + h * 64 + lane] * av[h * 64 + lane];
                #pragma unroll
                for (int m = 32; m >= 1; m >>= 1) p += __shfl_xor(p, m, 64);
                if (lane == 0) alph[br * 8 + k] = LOG2E * p;
            }
        }
    } else {
        for (int i = tid; i < 8192; i += 256) pooled[i] = 0.f;
    }
}

// per-bucket CSR: compact bases from bcur scan, local degrees, scatter src.
__global__ __launch_bounds__(256) void csr_kernel(
    const int* __restrict__ bcur, const unsigned* __restrict__ epair,
    int* __restrict__ rs, int* __restrict__ csr, int N, int E, int NB){
    int bid = blockIdx.x;
    int br = (bid >= NB) ? 1 : 0;
    int b = bid - br * NB;
    __shared__ int base2[128];
    __shared__ int deg[512], st[512];
    int tid = threadIdx.x, lane = tid & 63, wid = tid >> 6;
    if (wid == 0){
        int b0 = (lane < NB) ? bcur[br * NB + lane] : 0;
        int b1 = (64 + lane < NB) ? bcur[br * NB + 64 + lane] : 0;
        int g0 = wave_incl_scan(b0, lane); int gt = __shfl(g0, 63, 64);
        int g1 = wave_incl_scan(b1, lane);
        base2[lane] = g0 - b0; base2[64 + lane] = gt + g1 - b1;
    }
    for (int i = tid; i < 512; i += 256) deg[i] = 0;
    __syncthreads();
    int ebase = base2[b];
    int ecnt = bcur[br * NB + b];
    int n0 = b << BSH;
    int nodes = min(512, N - n0);
    const unsigned* ep = epair + ((size_t)br * NB + b) * ARENA;
    for (int i = tid; i < ecnt; i += 256) atomicAdd(&deg[ep[i] & 511u], 1);
    __syncthreads();
    if (wid == 0){
        int carry = 0;
        #pragma unroll
        for (int c = 0; c < 8; ++c){
            int v = deg[c * 64 + lane];
            int s = wave_incl_scan(v, lane);
            st[c * 64 + lane] = carry + s - v;
            carry += __shfl(s, 63, 64);
        }
    }
    __syncthreads();
    int* rsb = rs + (size_t)br * (N + 1);
    for (int i = tid; i < nodes; i += 256) rsb[n0 + i] = ebase + st[i];
    if (b == NB - 1 && tid == 0) rsb[N] = ebase + ecnt;
    for (int i = tid; i < 512; i += 256) deg[i] = st[i];
    __syncthreads();
    int* csrb = csr + (size_t)br * E + ebase;
    for (int i = tid; i < ecnt; i += 256){
        unsigned p = ep[i];
        int pos = atomicAdd(&deg[p & 511u], 1);
        csrb[pos] = (int)(p >> BSH);
    }
}

// Low-rank GAT1 aggregation (8 lanes/node, logits on-the-fly, 4-slot guarded
// batched gathers) + h1 reconstruction + MFMA + layer-2 logits.
// Block = 32 nodes, 4 waves.
__global__ __launch_bounds__(256) void a1f2_kernel(
    const float* __restrict__ xB, const float* __restrict__ xT,
    const float* __restrict__ alph,
    const int* __restrict__ csr, const int* __restrict__ rs,
    const float* __restrict__ W1b, const float* __restrict__ W1t,
    const float* __restrict__ b1b, const float* __restrict__ b1t,
    const unsigned short* __restrict__ w2T,
    const float* __restrict__ a2sb, const float* __restrict__ a2st,
    const float* __restrict__ a2db, const float* __restrict__ a2dt,
    unsigned short* __restrict__ xl2h, float* __restrict__ es2, float* __restrict__ ed2,
    int N, int E){
    int bid = blockIdx.x;
    int br = bid & 1;                 // branch parity == XCD parity class
    int n0 = (bid >> 1) << 5;         // 32 nodes per block
    const float* x  = br ? xT : xB;
    const int* cs = csr + (size_t)br * E;
    const int* rsb = rs + (size_t)br * (N + 1);
    const float* W1 = br ? W1t : W1b;
    const float* b1 = br ? b1t : b1b;
    const float* a2s = br ? a2st : a2sb;
    const float* a2d = br ? a2dt : a2db;
    const float* al = alph + br * 8;
    float as0x = al[0], as0y = al[1], as1x = al[2], as1y = al[3];
    float ad0x = al[4], ad0y = al[5], ad1x = al[6], ad1y = al[7];

    __shared__ float sacc[32][6];     // per node: d0, s0x, s0y, d1, s1x, s1y
    __shared__ unsigned hl[32][68];   // h1 tile, packed bf16 pairs, padded
    __shared__ float psa[4][32], pda[4][32];
    int tid = threadIdx.x, lane = tid & 63, w = tid >> 6;
    int g = lane >> 3, sl = lane & 7;
    int row = w * 8 + g;
    int n = n0 + row;
    bool valid = n < N;

    // ---- aggregation: 8 lanes per node, batched guarded gathers ----
    float2 xn = ((const float2*)x)[valid ? n : 0];
    float edv0 = ad0x * xn.x + ad0y * xn.y;      // dst logits (pre-scaled)
    float edv1 = ad1x * xn.x + ad1y * xn.y;
    int beg = 0, end = 0;
    if (valid){ beg = rsb[n]; end = rsb[n + 1]; }
    float d0 = 0.f, s0x = 0.f, s0y = 0.f, d1 = 0.f, s1x = 0.f, s1y = 0.f;
    if (valid && sl == 0){            // self-loop term
        float e0 = as0x * xn.x + as0y * xn.y;
        float e1 = as1x * xn.x + as1y * xn.y;
        float w0 = exp2f(leaky02(e0 + edv0));
        float w1 = exp2f(leaky02(e1 + edv1));
        d0 = w0; s0x = w0 * xn.x; s0y = w0 * xn.y;
        d1 = w1; s1x = w1 * xn.x; s1y = w1 * xn.y;
    }
    int j0 = beg + sl;
    // batch the first 4 strided edges of this lane (covers deg <= 32)
    int sidx0, sidx1, sidx2, sidx3;
    float m0, m1, m2, m3;
    {
        int j;
        j = j0;      m0 = (j < end) ? 1.f : 0.f; sidx0 = (j < end) ? cs[j] : 0;
        j = j0 + 8;  m1 = (j < end) ? 1.f : 0.f; sidx1 = (j < end) ? cs[j] : 0;
        j = j0 + 16; m2 = (j < end) ? 1.f : 0.f; sidx2 = (j < end) ? cs[j] : 0;
        j = j0 + 24; m3 = (j < end) ? 1.f : 0.f; sidx3 = (j < end) ? cs[j] : 0;
    }
    float2 xv0 = ((const float2*)x)[sidx0];
    float2 xv1 = ((const float2*)x)[sidx1];
    float2 xv2 = ((const float2*)x)[sidx2];
    float2 xv3 = ((const float2*)x)[sidx3];
    #define ACC_EDGE(XV, M) { \
        float e0 = as0x * XV.x + as0y * XV.y; \
        float e1 = as1x * XV.x + as1y * XV.y; \
        float w0 = M * exp2f(leaky02(e0 + edv0)); \
        float w1 = M * exp2f(leaky02(e1 + edv1)); \
        d0 += w0; s0x += w0 * XV.x; s0y += w0 * XV.y; \
        d1 += w1; s1x += w1 * XV.x; s1y += w1 * XV.y; }
    ACC_EDGE(xv0, m0) ACC_EDGE(xv1, m1) ACC_EDGE(xv2, m2) ACC_EDGE(xv3, m3)
    #undef ACC_EDGE
    // rare tail: lanes with more than 4 strided edges
    for (int j = j0 + 32; j < end; j += 8){
        int s = cs[j];
        float2 xv = ((const float2*)x)[s];
        float e0 = as0x * xv.x + as0y * xv.y;
        float e1 = as1x * xv.x + as1y * xv.y;
        float w0 = exp2f(leaky02(e0 + edv0));
        float w1 = exp2f(leaky02(e1 + edv1));
        d0 += w0; s0x += w0 * xv.x; s0y += w0 * xv.y;
        d1 += w1; s1x += w1 * xv.x; s1y += w1 * xv.y;
    }
    #pragma unroll
    for (int m = 1; m < 8; m <<= 1){
        d0  += __shfl_xor(d0, m, 64);
        s0x += __shfl_xor(s0x, m, 64);
        s0y += __shfl_xor(s0y, m, 64);
        d1  += __shfl_xor(d1, m, 64);
        s1x += __shfl_xor(s1x, m, 64);
        s1y += __shfl_xor(s1y, m, 64);
    }
    if (sl == 0){
        sacc[row][0] = d0; sacc[row][1] = s0x; sacc[row][2] = s0y;
        sacc[row][3] = d1; sacc[row][4] = s1x; sacc[row][5] = s1y;
    }
    __syncthreads();

    // ---- reconstruct h1 = elu(W1^T sacc / denom + b1), 8 rows per wave ----
    int h = lane >> 5;
    float2 w0c = ((const float2*)W1)[lane];          // W1[0, 2l..2l+1]
    float2 w1c = ((const float2*)(W1 + 128))[lane];  // W1[1, 2l..2l+1]
    float b1lo = b1[lane * 2], b1hi = b1[lane * 2 + 1];
    #pragma unroll
    for (int nn = 0; nn < 8; ++nn){
        int r2 = w * 8 + nn;
        int nr = n0 + r2;
        float dinv = 1.f / sacc[r2][3 * h];
        float sx = sacc[r2][3 * h + 1], sy = sacc[r2][3 * h + 2];
        float va = (sx * w0c.x + sy * w1c.x) * dinv + b1lo;
        float vb = (sx * w0c.y + sy * w1c.y) * dinv + b1hi;
        hl[r2][lane] = (nr < N) ? packbf(elu1(va), elu1(vb)) : 0u;
    }

    int lr = lane & 15, lq = lane >> 4;
    // B fragments straight from global bf16 W2T (L1-resident 16KB/branch)
    const unsigned short* wtp = w2T + br * 8192 + (w * 16 + lr) * 128 + lq * 8;
    short8v bf0 = *(const short8v*)(wtp);
    short8v bf1 = *(const short8v*)(wtp + 32);
    short8v bf2 = *(const short8v*)(wtp + 64);
    short8v bf3 = *(const short8v*)(wtp + 96);
    float a2sv = a2s[w * 16 + lr];
    float a2dv = a2d[w * 16 + lr];
    __syncthreads();
    // ---- MFMA: 2 row-tiles x this wave's 16-col tile ----
    #pragma unroll
    for (int rt = 0; rt < 2; ++rt){
        int rb = rt << 4;
        f32x4 ac = {0.f, 0.f, 0.f, 0.f};
        ac = __builtin_amdgcn_mfma_f32_16x16x32_bf16(*(const short8v*)&hl[rb + lr][lq * 4], bf0, ac, 0, 0, 0);
        ac = __builtin_amdgcn_mfma_f32_16x16x32_bf16(*(const short8v*)&hl[rb + lr][16 + lq * 4], bf1, ac, 0, 0, 0);
        ac = __builtin_amdgcn_mfma_f32_16x16x32_bf16(*(const short8v*)&hl[rb + lr][32 + lq * 4], bf2, ac, 0, 0, 0);
        ac = __builtin_amdgcn_mfma_f32_16x16x32_bf16(*(const short8v*)&hl[rb + lr][48 + lq * 4], bf3, ac, 0, 0, 0);
        #pragma unroll
        for (int reg = 0; reg < 4; ++reg){
            int r = rb + lq * 4 + reg;
            int nr = n0 + r;
            float v = ac[reg];
            if (nr < N)
                xl2h[((size_t)br * N + nr) * 64 + w * 16 + lr] = (unsigned short)f2bf(v);
            float ps = v * a2sv, pd = v * a2dv;
            ps += __shfl_xor(ps, 1, 64); ps += __shfl_xor(ps, 2, 64);
            ps += __shfl_xor(ps, 4, 64); ps += __shfl_xor(ps, 8, 64);
            pd += __shfl_xor(pd, 1, 64); pd += __shfl_xor(pd, 2, 64);
            pd += __shfl_xor(pd, 4, 64); pd += __shfl_xor(pd, 8, 64);
            if (lr == 0){ psa[w][r] = ps; pda[w][r] = pd; }
        }
    }
    __syncthreads();
    if (tid < 32){
        int nr = n0 + tid;
        if (nr < N)
            es2[(size_t)br * N + nr] = LOG2E * (psa[0][tid] + psa[1][tid] + psa[2][tid] + psa[3][tid]);
    } else if (tid < 64){
        int r = tid - 32;
        int nr = n0 + r;
        if (nr < N)
            ed2[(size_t)br * N + nr] = LOG2E * (pda[0][r] + pda[1][r] + pda[2][r] + pda[3][r]);
    }
}

// Fused GAT2 aggregation + per-graph pooled sums (R15 structure).
// Edge list + weights hoisted to lanes; 16-deep batches over the 8-rounded
// edge count, with a single 8-deep batch for the remainder.
__global__ __launch_bounds__(256) void a2pl_kernel(
    const unsigned short* __restrict__ xl2h, const float* __restrict__ es2, const float* __restrict__ ed2,
    const int* __restrict__ csr, const int* __restrict__ rs,
    const float* __restrict__ b2b, const float* __restrict__ b2t,
    const int* __restrict__ batchb, const int* __restrict__ batcht,
    float* __restrict__ pooled, int N, int E){
    int bid = blockIdx.x;
    int br = bid & 1;                 // branch parity == XCD parity class
    int tid = threadIdx.x, lane = tid & 63, w = tid >> 6;
    int n = ((bid >> 1) << 2) + w;
    const unsigned short* xlt = xl2h + (size_t)br * N * 64;
    const float* es = es2 + (size_t)br * N;
    const float* ed = ed2 + (size_t)br * N;
    const int* cs = csr + (size_t)br * E;
    const int* rsb = rs + (size_t)br * (N + 1);
    const float* b2 = br ? b2t : b2b;
    const int* batch = br ? batcht : batchb;
    float hv = 0.f;
    int g = -1;
    if (n < N){
        g = batch[n];
        float edn = ed[n];
        float wself = exp2f(leaky02(es[n] + edn));
        float denom = wself;
        float acc = wself * bfs(xlt[(unsigned)(n * 64) + lane]);
        int beg = rsb[n];
        int end = rsb[n + 1];
        for (int base = beg; base < end; base += 64){
            int cnt = min(64, end - base);
            int myidx = cs[base + min(lane, cnt - 1)];
            float wmine = (lane < cnt) ? exp2f(leaky02(es[myidx] + edn)) : 0.f;
            float ws = wmine;
            #pragma unroll
            for (int m = 1; m < 64; m <<= 1) ws += __shfl_xor(ws, m, 64);
            denom += ws;
            int cntR = (cnt + 7) & ~7;
            int q0 = 0;
            for (; q0 + 16 <= cntR; q0 += 16){
                float vv[16];
                #pragma unroll
                for (int qq = 0; qq < 16; ++qq){
                    int s = __builtin_amdgcn_readlane(myidx, q0 + qq);
                    vv[qq] = bfs(xlt[(unsigned)(s * 64) + lane]);
                }
                #pragma unroll
                for (int qq = 0; qq < 16; ++qq){
                    float wq = __uint_as_float(
                        __builtin_amdgcn_readlane(__float_as_uint(wmine), q0 + qq));
                    acc += wq * vv[qq];
                }
            }
            if (q0 < cntR){
                float vv[8];
                #pragma unroll
                for (int qq = 0; qq < 8; ++qq){
                    int s = __builtin_amdgcn_readlane(myidx, q0 + qq);
                    vv[qq] = bfs(xlt[(unsigned)(s * 64) + lane]);
                }
                #pragma unroll
                for (int qq = 0; qq < 8; ++qq){
                    float wq = __uint_as_float(
                        __builtin_amdgcn_readlane(__float_as_uint(wmine), q0 + qq));
                    acc += wq * vv[qq];
                }
            }
        }
        hv = elu1(acc / denom + b2[lane]);
    }
    __shared__ float red[4][64];
    __shared__ int gid[4];
    red[w][lane] = hv;
    if (lane == 0) gid[w] = g;
    __syncthreads();
    if (w == 0){
        int g0 = gid[0], g1 = gid[1], g2 = gid[2], g3 = gid[3];
        float* pb = pooled + (size_t)br * 4096;
        if (g0 >= 0 && g0 == g1 && g1 == g2 && g2 == g3){
            float s = (red[0][lane] + red[1][lane]) + (red[2][lane] + red[3][lane]);
            atomicAdd(&pb[g0 * 64 + lane], s);
        } else {
            #pragma unroll
            for (int q = 0; q < 4; ++q)
                if (gid[q] >= 0) atomicAdd(&pb[gid[q] * 64 + lane], red[q][lane]);
        }
    }
}

// counts (binary search on sorted batch) + branch MLPs + combine + final head
__global__ __launch_bounds__(1024) void tail_kernel(
    const float* __restrict__ pooled,
    const int* __restrict__ batchb, const int* __restrict__ batcht,
    const float* __restrict__ M1wb, const float* __restrict__ M1bb,
    const float* __restrict__ M2wb, const float* __restrict__ M2bb,
    const float* __restrict__ M1wt, const float* __restrict__ M1bt,
    const float* __restrict__ M2wt, const float* __restrict__ M2bt,
    const float* __restrict__ Fw1, const float* __restrict__ Fb1,
    const float* __restrict__ Fw2, const float* __restrict__ Fb2,
    float* __restrict__ out, int N){
    __shared__ float P[8192];
    __shared__ float H[8192];
    __shared__ float cl[128];
    int t = threadIdx.x;
    if (t < 128){
        int br = t >> 6, g = t & 63;
        const int* batch = br ? batcht : batchb;
        int lo = 0, hi = N;
        while (lo < hi){ int mid = (lo + hi) >> 1; if (batch[mid] < g) lo = mid + 1; else hi = mid; }
        int beg = lo;
        hi = N;
        while (lo < hi){ int mid = (lo + hi) >> 1; if (batch[mid] < g + 1) lo = mid + 1; else hi = mid; }
        cl[t] = (float)(lo - beg);
    }
    __syncthreads();
    for (int i = t; i < 8192; i += 1024)
        P[i] = pooled[i] / fmaxf(cl[i >> 6], 1.f);
    __syncthreads();
    for (int i = t; i < 8192; i += 1024){
        int br = i >> 12, r = (i >> 6) & 63, c = i & 63;
        const float* M1w = br ? M1wt : M1wb;
        const float* M1b = br ? M1bt : M1bb;
        float acc = M1b[c];
        int pb = (br << 12) + (r << 6);
        #pragma unroll 8
        for (int k = 0; k < 64; ++k) acc += P[pb + k] * M1w[(k << 6) + c];
        H[i] = fmaxf(acc, 0.f);
    }
    __syncthreads();
    for (int i = t; i < 8192; i += 1024){
        int br = i >> 12, r = (i >> 6) & 63, c = i & 63;
        const float* M2w = br ? M2wt : M2wb;
        const float* M2b = br ? M2bt : M2bb;
        float acc = M2b[c];
        int hb = (br << 12) + (r << 6);
        #pragma unroll 8
        for (int k = 0; k < 64; ++k) acc += H[hb + k] * M2w[(k << 6) + c];
        P[i] = acc;
    }
    __syncthreads();
    for (int i = t; i < 4096; i += 1024) H[i] = P[i] * P[4096 + i];
    __syncthreads();
    for (int i = t; i < 4096; i += 1024){
        int r = i >> 6, c = i & 63;
        float acc = Fb1[c];
        #pragma unroll 8
        for (int k = 0; k < 64; ++k) acc += H[(r << 6) + k] * Fw1[(k << 6) + c];
        P[i] = fmaxf(acc, 0.f);
    }
    __syncthreads();
    if (t < 128){
        int r = t >> 1, jc = t & 1;
        float acc = Fb2[jc];
        #pragma unroll 8
        for (int k = 0; k < 64; ++k) acc += P[(r << 6) + k] * Fw2[k * 2 + jc];
        out[t] = tanhf(acc);
    }
}

extern "C" void kernel_launch(void* const* d_in, const int* in_sizes, int n_in,
                              void* d_out, int out_size, void* d_ws, size_t ws_size,
                              hipStream_t stream){
    const int N = in_sizes[0] / 2;
    const int E = in_sizes[1] / 2;
    const int NB = (N + 511) >> BSH;   // nodes-per-bucket = 512, NB <= 128

    char* ws = (char*)d_ws;
    size_t off = 0;
    auto alloc = [&](size_t bytes) -> char* {
        char* p = ws + off;
        off += (bytes + 255) & ~(size_t)255;
        return p;
    };
    unsigned short* XL2h = (unsigned short*)alloc((size_t)2 * N * 64 * 2);  // EPAIR aliases this
    float* ES2 = (float*)alloc((size_t)2 * N * 4);
    float* ED2 = (float*)alloc((size_t)2 * N * 4);
    int* RS  = (int*)alloc((size_t)2 * (N + 1) * 4);
    int* CSR = (int*)alloc((size_t)2 * E * 4);
    int* BCUR = (int*)alloc((size_t)2 * NB * 4);
    float* POOLED = (float*)alloc(8192 * 4);
    unsigned short* W2T = (unsigned short*)alloc(2 * 8192 * 2);
    float* ALPH = (float*)alloc(16 * 4);
    unsigned* EPAIR = (unsigned*)XL2h;   // 2*NB*ARENA*4 <= 2*N*128 bytes; dead after csr

    const float* xb   = (const float*)d_in[0];
    const int*   eib  = (const int*)  d_in[1];
    const int*   batchb = (const int*)d_in[2];
    const float* W1b  = (const float*)d_in[3];
    const float* a1sb = (const float*)d_in[4];
    const float* a1db = (const float*)d_in[5];
    const float* b1b  = (const float*)d_in[6];
    const float* W2b  = (const float*)d_in[7];
    const float* a2sb = (const float*)d_in[8];
    const float* a2db = (const float*)d_in[9];
    const float* b2b  = (const float*)d_in[10];
    const float* M1wb = (const float*)d_in[11];
    const float* M1bb = (const float*)d_in[12];
    const float* M2wb = (const float*)d_in[13];
    const float* M2bb = (const float*)d_in[14];
    const float* xt   = (const float*)d_in[15];
    const int*   eit  = (const int*)  d_in[16];
    const int*   batcht = (const int*)d_in[17];
    const float* W1t  = (const float*)d_in[18];
    const float* a1st = (const float*)d_in[19];
    const float* a1dt = (const float*)d_in[20];
    const float* b1t  = (const float*)d_in[21];
    const float* W2t  = (const float*)d_in[22];
    const float* a2st = (const float*)d_in[23];
    const float* a2dt = (const float*)d_in[24];
    const float* b2t  = (const float*)d_in[25];
    const float* M1wt = (const float*)d_in[26];
    const float* M1bt = (const float*)d_in[27];
    const float* M2wt = (const float*)d_in[28];
    const float* M2bt = (const float*)d_in[29];
    const float* Fw1  = (const float*)d_in[30];
    const float* Fb1  = (const float*)d_in[31];
    const float* Fw2  = (const float*)d_in[32];
    const float* Fb2  = (const float*)d_in[33];

    const int nodeBlocks = (N + 3) / 4;
    const int histBlocks = (E + CHUNK - 1) / CHUNK;
    const int tilesPer   = (N + 31) / 32;

    hipMemsetAsync(BCUR, 0, (size_t)2 * NB * 4, stream);
    preb_kernel<<<2 * histBlocks + 3, 256, 0, stream>>>(
        W1b, W1t, a1sb, a1st, a1db, a1dt, eib, eit, W2b, W2t,
        BCUR, EPAIR, W2T, ALPH, POOLED, N, E, NB, histBlocks);
    csr_kernel<<<2 * NB, 256, 0, stream>>>(BCUR, EPAIR, RS, CSR, N, E, NB);
    a1f2_kernel<<<2 * tilesPer, 256, 0, stream>>>(
        xb, xt, ALPH, CSR, RS, W1b, W1t, b1b, b1t, W2T,
        a2sb, a2st, a2db, a2dt, XL2h, ES2, ED2, N, E);
    a2pl_kernel<<<2 * nodeBlocks, 256, 0, stream>>>(
        XL2h, ES2, ED2, CSR, RS, b2b, b2t, batchb, batcht, POOLED, N, E);
    tail_kernel<<<1, 1024, 0, stream>>>(POOLED, batchb, batcht,
        M1wb, M1bb, M2wb, M2bb, M1wt, M1bt, M2wt, M2bt,
        Fw1, Fb1, Fw2, Fb2, (float*)d_out, N);
}

// Round 18
// 196.745 us; speedup vs baseline: 1.0567x; 1.0078x over previous
//
#include <hip/hip_runtime.h>
#include <math.h>

// ---------------------------------------------------------------------------
// DeepONet/GAT, fused pipeline (R18 = R17 + occupancy fixes for CSR build):
//   memset: BCUR (tiny)
//   preb  : W2->bf16^T + rank-2 logit coeffs + POOLED zero + bin (2048 chunks)
//   csr   : per-bucket CSR build, 1024 threads/block
//   a1f2  : LOW-RANK GAT1 agg (4-slot guarded batched gathers, 8 lanes/node)
//           -> h1 = W1^T·sacc -> MFMA -> xl2 + layer-2 logits
//   a2pl  : GAT2 agg (R15 structure: 16-deep + 8-deep rounds)
//   tail  : counts + branch MLPs + combine + final head
// Buckets: 512 nodes (BSH=9), NB <= 128 (N <= 65536), arena 12288 edges.
// ---------------------------------------------------------------------------

#define BSH 9
#define BINCH 2048
#define ARENA 12288
#define LOG2E 1.44269504088896f

using short8v = __attribute__((ext_vector_type(8))) short;
using f32x4  = __attribute__((ext_vector_type(4))) float;

__device__ __forceinline__ float leaky02(float x){ return fmaxf(x, 0.2f * x); }
__device__ __forceinline__ float elu1(float x){ return x > 0.f ? x : expm1f(x); }
__device__ __forceinline__ unsigned f2bf(float a){
    unsigned u = __float_as_uint(a);
    return (u + 0x7FFFu + ((u >> 16) & 1u)) >> 16;
}
__device__ __forceinline__ unsigned packbf(float a, float b){ return f2bf(a) | (f2bf(b) << 16); }
__device__ __forceinline__ float bflo(unsigned p){ return __uint_as_float(p << 16); }
__device__ __forceinline__ float bfhi(unsigned p){ return __uint_as_float(p & 0xFFFF0000u); }
__device__ __forceinline__ float bfs(unsigned short s){ return __uint_as_float(((unsigned)s) << 16); }

__device__ __forceinline__ int wave_incl_scan(int v, int lane){
    #pragma unroll
    for (int d = 1; d < 64; d <<= 1){ int u = __shfl_up(v, (unsigned)d, 64); if (lane >= d) v += u; }
    return v;
}

// W2 transpose + alpha coeffs + POOLED zero + edge binning, grid-split.
__global__ __launch_bounds__(256) void preb_kernel(
    const float* __restrict__ W1b, const float* __restrict__ W1t,
    const float* __restrict__ a1sb, const float* __restrict__ a1st,
    const float* __restrict__ a1db, const float* __restrict__ a1dt,
    const int* __restrict__ eib, const int* __restrict__ eit,
    const float* __restrict__ W2b, const float* __restrict__ W2t,
    int* __restrict__ bcur, unsigned* __restrict__ epair,
    unsigned short* __restrict__ w2T, float* __restrict__ alph,
    float* __restrict__ pooled,
    int N, int E, int NB, int histBlocks){
    int bid = blockIdx.x;
    int tid = threadIdx.x;
    __shared__ int hist[128], gpos[128];
    __shared__ int slots[BINCH];
    if (bid < 2 * histBlocks){
        // ---- bin: bucket-sort one 2048-edge chunk into fixed arenas ----
        int br = (bid >= histBlocks) ? 1 : 0;
        int cb = bid - br * histBlocks;
        const int* ei = br ? eit : eib;
        int start = cb * BINCH;
        int cnt = min(BINCH, E - start);
        for (int i = tid; i < 128; i += 256) hist[i] = 0;
        __syncthreads();
        const int* dstp = ei + E + start;
        const int* srcp = ei + start;
        for (int li = tid; li < cnt; li += 256){
            int b = dstp[li] >> BSH;
            slots[li] = atomicAdd(&hist[b], 1);
        }
        __syncthreads();
        if (tid < NB){
            int h0 = hist[tid];
            gpos[tid] = (h0 > 0) ? atomicAdd(&bcur[br * NB + tid], h0) : 0;
        }
        __syncthreads();
        unsigned* ep = epair + (size_t)br * NB * ARENA;
        for (int li = tid; li < cnt; li += 256){
            int d = dstp[li];
            int b = d >> BSH;
            ep[(size_t)b * ARENA + gpos[b] + slots[li]] =
                ((unsigned)srcp[li] << BSH) | (unsigned)(d & ((1 << BSH) - 1));
        }
        return;
    }
    bid -= 2 * histBlocks;
    if (bid < 2){
        // W2T[c][k] = bf16(W2[k][c]) + alpha coeffs, per branch
        int br = bid;
        const float* W2 = br ? W2t : W2b;
        for (int i = tid; i < 8192; i += 256){
            int c = i >> 7, k = i & 127;
            w2T[br * 8192 + i] = (unsigned short)f2bf(W2[k * 64 + c]);
        }
        if (tid < 64){
            const float* W1  = br ? W1t  : W1b;
            const float* a1s = br ? a1st : a1sb;
            const float* a1d = br ? a1dt : a1db;
            int lane = tid;
            for (int k = 0; k < 8; ++k){
                int sd = k >> 2, h = (k >> 1) & 1, xr = k & 1;
                const float* av = sd ? a1d : a1s;
                float p = W1[xr * 128 + h * 64 + lane] * av[h * 64 + lane];
                #pragma unroll
                for (int m = 32; m >= 1; m >>= 1) p += __shfl_xor(p, m, 64);
                if (lane == 0) alph[br * 8 + k] = LOG2E * p;
            }
        }
    } else {
        for (int i = tid; i < 8192; i += 256) pooled[i] = 0.f;
    }
}

// per-bucket CSR: 1024 threads/block; compact bases from bcur scan (wave 0),
// local degrees, scatter src.
__global__ __launch_bounds__(1024) void csr_kernel(
    const int* __restrict__ bcur, const unsigned* __restrict__ epair,
    int* __restrict__ rs, int* __restrict__ csr, int N, int E, int NB){
    int bid = blockIdx.x;
    int br = (bid >= NB) ? 1 : 0;
    int b = bid - br * NB;
    __shared__ int base2[128];
    __shared__ int deg[512], st[512];
    int tid = threadIdx.x, lane = tid & 63, wid = tid >> 6;
    if (wid == 0){
        int b0 = (lane < NB) ? bcur[br * NB + lane] : 0;
        int b1 = (64 + lane < NB) ? bcur[br * NB + 64 + lane] : 0;
        int g0 = wave_incl_scan(b0, lane); int gt = __shfl(g0, 63, 64);
        int g1 = wave_incl_scan(b1, lane);
        base2[lane] = g0 - b0; base2[64 + lane] = gt + g1 - b1;
    }
    for (int i = tid; i < 512; i += 1024) deg[i] = 0;
    __syncthreads();
    int ebase = base2[b];
    int ecnt = bcur[br * NB + b];
    int n0 = b << BSH;
    int nodes = min(512, N - n0);
    const unsigned* ep = epair + ((size_t)br * NB + b) * ARENA;
    for (int i = tid; i < ecnt; i += 1024) atomicAdd(&deg[ep[i] & 511u], 1);
    __syncthreads();
    if (wid == 0){
        int carry = 0;
        #pragma unroll
        for (int c = 0; c < 8; ++c){
            int v = deg[c * 64 + lane];
            int s = wave_incl_scan(v, lane);
            st[c * 64 + lane] = carry + s - v;
            carry += __shfl(s, 63, 64);
        }
    }
    __syncthreads();
    int* rsb = rs + (size_t)br * (N + 1);
    for (int i = tid; i < nodes; i += 1024) rsb[n0 + i] = ebase + st[i];
    if (b == NB - 1 && tid == 0) rsb[N] = ebase + ecnt;
    for (int i = tid; i < 512; i += 1024) deg[i] = st[i];
    __syncthreads();
    int* csrb = csr + (size_t)br * E + ebase;
    for (int i = tid; i < ecnt; i += 1024){
        unsigned p = ep[i];
        int pos = atomicAdd(&deg[p & 511u], 1);
        csrb[pos] = (int)(p >> BSH);
    }
}

// Low-rank GAT1 aggregation (8 lanes/node, logits on-the-fly, 4-slot guarded
// batched gathers) + h1 reconstruction + MFMA + layer-2 logits.
// Block = 32 nodes, 4 waves.
__global__ __launch_bounds__(256) void a1f2_kernel(
    const float* __restrict__ xB, const float* __restrict__ xT,
    const float* __restrict__ alph,
    const int* __restrict__ csr, const int* __restrict__ rs,
    const float* __restrict__ W1b, const float* __restrict__ W1t,
    const float* __restrict__ b1b, const float* __restrict__ b1t,
    const unsigned short* __restrict__ w2T,
    const float* __restrict__ a2sb, const float* __restrict__ a2st,
    const float* __restrict__ a2db, const float* __restrict__ a2dt,
    unsigned short* __restrict__ xl2h, float* __restrict__ es2, float* __restrict__ ed2,
    int N, int E){
    int bid = blockIdx.x;
    int br = bid & 1;                 // branch parity == XCD parity class
    int n0 = (bid >> 1) << 5;         // 32 nodes per block
    const float* x  = br ? xT : xB;
    const int* cs = csr + (size_t)br * E;
    const int* rsb = rs + (size_t)br * (N + 1);
    const float* W1 = br ? W1t : W1b;
    const float* b1 = br ? b1t : b1b;
    const float* a2s = br ? a2st : a2sb;
    const float* a2d = br ? a2dt : a2db;
    const float* al = alph + br * 8;
    float as0x = al[0], as0y = al[1], as1x = al[2], as1y = al[3];
    float ad0x = al[4], ad0y = al[5], ad1x = al[6], ad1y = al[7];

    __shared__ float sacc[32][6];     // per node: d0, s0x, s0y, d1, s1x, s1y
    __shared__ unsigned hl[32][68];   // h1 tile, packed bf16 pairs, padded
    __shared__ float psa[4][32], pda[4][32];
    int tid = threadIdx.x, lane = tid & 63, w = tid >> 6;
    int g = lane >> 3, sl = lane & 7;
    int row = w * 8 + g;
    int n = n0 + row;
    bool valid = n < N;

    // ---- aggregation: 8 lanes per node, batched guarded gathers ----
    float2 xn = ((const float2*)x)[valid ? n : 0];
    float edv0 = ad0x * xn.x + ad0y * xn.y;      // dst logits (pre-scaled)
    float edv1 = ad1x * xn.x + ad1y * xn.y;
    int beg = 0, end = 0;
    if (valid){ beg = rsb[n]; end = rsb[n + 1]; }
    float d0 = 0.f, s0x = 0.f, s0y = 0.f, d1 = 0.f, s1x = 0.f, s1y = 0.f;
    if (valid && sl == 0){            // self-loop term
        float e0 = as0x * xn.x + as0y * xn.y;
        float e1 = as1x * xn.x + as1y * xn.y;
        float w0 = exp2f(leaky02(e0 + edv0));
        float w1 = exp2f(leaky02(e1 + edv1));
        d0 = w0; s0x = w0 * xn.x; s0y = w0 * xn.y;
        d1 = w1; s1x = w1 * xn.x; s1y = w1 * xn.y;
    }
    int j0 = beg + sl;
    // batch the first 4 strided edges of this lane (covers deg <= 32)
    int sidx0, sidx1, sidx2, sidx3;
    float m0, m1, m2, m3;
    {
        int j;
        j = j0;      m0 = (j < end) ? 1.f : 0.f; sidx0 = (j < end) ? cs[j] : 0;
        j = j0 + 8;  m1 = (j < end) ? 1.f : 0.f; sidx1 = (j < end) ? cs[j] : 0;
        j = j0 + 16; m2 = (j < end) ? 1.f : 0.f; sidx2 = (j < end) ? cs[j] : 0;
        j = j0 + 24; m3 = (j < end) ? 1.f : 0.f; sidx3 = (j < end) ? cs[j] : 0;
    }
    float2 xv0 = ((const float2*)x)[sidx0];
    float2 xv1 = ((const float2*)x)[sidx1];
    float2 xv2 = ((const float2*)x)[sidx2];
    float2 xv3 = ((const float2*)x)[sidx3];
    #define ACC_EDGE(XV, M) { \
        float e0 = as0x * XV.x + as0y * XV.y; \
        float e1 = as1x * XV.x + as1y * XV.y; \
        float w0 = M * exp2f(leaky02(e0 + edv0)); \
        float w1 = M * exp2f(leaky02(e1 + edv1)); \
        d0 += w0; s0x += w0 * XV.x; s0y += w0 * XV.y; \
        d1 += w1; s1x += w1 * XV.x; s1y += w1 * XV.y; }
    ACC_EDGE(xv0, m0) ACC_EDGE(xv1, m1) ACC_EDGE(xv2, m2) ACC_EDGE(xv3, m3)
    #undef ACC_EDGE
    // rare tail: lanes with more than 4 strided edges
    for (int j = j0 + 32; j < end; j += 8){
        int s = cs[j];
        float2 xv = ((const float2*)x)[s];
        float e0 = as0x * xv.x + as0y * xv.y;
        float e1 = as1x * xv.x + as1y * xv.y;
        float w0 = exp2f(leaky02(e0 + edv0));
        float w1 = exp2f(leaky02(e1 + edv1));
        d0 += w0; s0x += w0 * xv.x; s0y += w0 * xv.y;
        d1 += w1; s1x += w1 * xv.x; s1y += w1 * xv.y;
    }
    #pragma unroll
    for (int m = 1; m < 8; m <<= 1){
        d0  += __shfl_xor(d0, m, 64);
        s0x += __shfl_xor(s0x, m, 64);
        s0y += __shfl_xor(s0y, m, 64);
        d1  += __shfl_xor(d1, m, 64);
        s1x += __shfl_xor(s1x, m, 64);
        s1y += __shfl_xor(s1y, m, 64);
    }
    if (sl == 0){
        sacc[row][0] = d0; sacc[row][1] = s0x; sacc[row][2] = s0y;
        sacc[row][3] = d1; sacc[row][4] = s1x; sacc[row][5] = s1y;
    }
    __syncthreads();

    // ---- reconstruct h1 = elu(W1^T sacc / denom + b1), 8 rows per wave ----
    int h = lane >> 5;
    float2 w0c = ((const float2*)W1)[lane];          // W1[0, 2l..2l+1]
    float2 w1c = ((const float2*)(W1 + 128))[lane];  // W1[1, 2l..2l+1]
    float b1lo = b1[lane * 2], b1hi = b1[lane * 2 + 1];
    #pragma unroll
    for (int nn = 0; nn < 8; ++nn){
        int r2 = w * 8 + nn;
        int nr = n0 + r2;
        float dinv = 1.f / sacc[r2][3 * h];
        float sx = sacc[r2][3 * h + 1], sy = sacc[r2][3 * h + 2];
        float va = (sx * w0c.x + sy * w1c.x) * dinv + b1lo;
        float vb = (sx * w0c.y + sy * w1c.y) * dinv + b1hi;
        hl[r2][lane] = (nr < N) ? packbf(elu1(va), elu1(vb)) : 0u;
    }

    int lr = lane & 15, lq = lane >> 4;
    // B fragments straight from global bf16 W2T (L1-resident 16KB/branch)
    const unsigned short* wtp = w2T + br * 8192 + (w * 16 + lr) * 128 + lq * 8;
    short8v bf0 = *(const short8v*)(wtp);
    short8v bf1 = *(const short8v*)(wtp + 32);
    short8v bf2 = *(const short8v*)(wtp + 64);
    short8v bf3 = *(const short8v*)(wtp + 96);
    float a2sv = a2s[w * 16 + lr];
    float a2dv = a2d[w * 16 + lr];
    __syncthreads();
    // ---- MFMA: 2 row-tiles x this wave's 16-col tile ----
    #pragma unroll
    for (int rt = 0; rt < 2; ++rt){
        int rb = rt << 4;
        f32x4 ac = {0.f, 0.f, 0.f, 0.f};
        ac = __builtin_amdgcn_mfma_f32_16x16x32_bf16(*(const short8v*)&hl[rb + lr][lq * 4], bf0, ac, 0, 0, 0);
        ac = __builtin_amdgcn_mfma_f32_16x16x32_bf16(*(const short8v*)&hl[rb + lr][16 + lq * 4], bf1, ac, 0, 0, 0);
        ac = __builtin_amdgcn_mfma_f32_16x16x32_bf16(*(const short8v*)&hl[rb + lr][32 + lq * 4], bf2, ac, 0, 0, 0);
        ac = __builtin_amdgcn_mfma_f32_16x16x32_bf16(*(const short8v*)&hl[rb + lr][48 + lq * 4], bf3, ac, 0, 0, 0);
        #pragma unroll
        for (int reg = 0; reg < 4; ++reg){
            int r = rb + lq * 4 + reg;
            int nr = n0 + r;
            float v = ac[reg];
            if (nr < N)
                xl2h[((size_t)br * N + nr) * 64 + w * 16 + lr] = (unsigned short)f2bf(v);
            float ps = v * a2sv, pd = v * a2dv;
            ps += __shfl_xor(ps, 1, 64); ps += __shfl_xor(ps, 2, 64);
            ps += __shfl_xor(ps, 4, 64); ps += __shfl_xor(ps, 8, 64);
            pd += __shfl_xor(pd, 1, 64); pd += __shfl_xor(pd, 2, 64);
            pd += __shfl_xor(pd, 4, 64); pd += __shfl_xor(pd, 8, 64);
            if (lr == 0){ psa[w][r] = ps; pda[w][r] = pd; }
        }
    }
    __syncthreads();
    if (tid < 32){
        int nr = n0 + tid;
        if (nr < N)
            es2[(size_t)br * N + nr] = LOG2E * (psa[0][tid] + psa[1][tid] + psa[2][tid] + psa[3][tid]);
    } else if (tid < 64){
        int r = tid - 32;
        int nr = n0 + r;
        if (nr < N)
            ed2[(size_t)br * N + nr] = LOG2E * (pda[0][r] + pda[1][r] + pda[2][r] + pda[3][r]);
    }
}

// Fused GAT2 aggregation + per-graph pooled sums (R15 structure).
// Edge list + weights hoisted to lanes; 16-deep batches over the 8-rounded
// edge count, with a single 8-deep batch for the remainder.
__global__ __launch_bounds__(256) void a2pl_kernel(
    const unsigned short* __restrict__ xl2h, const float* __restrict__ es2, const float* __restrict__ ed2,
    const int* __restrict__ csr, const int* __restrict__ rs,
    const float* __restrict__ b2b, const float* __restrict__ b2t,
    const int* __restrict__ batchb, const int* __restrict__ batcht,
    float* __restrict__ pooled, int N, int E){
    int bid = blockIdx.x;
    int br = bid & 1;                 // branch parity == XCD parity class
    int tid = threadIdx.x, lane = tid & 63, w = tid >> 6;
    int n = ((bid >> 1) << 2) + w;
    const unsigned short* xlt = xl2h + (size_t)br * N * 64;
    const float* es = es2 + (size_t)br * N;
    const float* ed = ed2 + (size_t)br * N;
    const int* cs = csr + (size_t)br * E;
    const int* rsb = rs + (size_t)br * (N + 1);
    const float* b2 = br ? b2t : b2b;
    const int* batch = br ? batcht : batchb;
    float hv = 0.f;
    int g = -1;
    if (n < N){
        g = batch[n];
        float edn = ed[n];
        float wself = exp2f(leaky02(es[n] + edn));
        float denom = wself;
        float acc = wself * bfs(xlt[(unsigned)(n * 64) + lane]);
        int beg = rsb[n];
        int end = rsb[n + 1];
        for (int base = beg; base < end; base += 64){
            int cnt = min(64, end - base);
            int myidx = cs[base + min(lane, cnt - 1)];
            float wmine = (lane < cnt) ? exp2f(leaky02(es[myidx] + edn)) : 0.f;
            float ws = wmine;
            #pragma unroll
            for (int m = 1; m < 64; m <<= 1) ws += __shfl_xor(ws, m, 64);
            denom += ws;
            int cntR = (cnt + 7) & ~7;
            int q0 = 0;
            for (; q0 + 16 <= cntR; q0 += 16){
                float vv[16];
                #pragma unroll
                for (int qq = 0; qq < 16; ++qq){
                    int s = __builtin_amdgcn_readlane(myidx, q0 + qq);
                    vv[qq] = bfs(xlt[(unsigned)(s * 64) + lane]);
                }
                #pragma unroll
                for (int qq = 0; qq < 16; ++qq){
                    float wq = __uint_as_float(
                        __builtin_amdgcn_readlane(__float_as_uint(wmine), q0 + qq));
                    acc += wq * vv[qq];
                }
            }
            if (q0 < cntR){
                float vv[8];
                #pragma unroll
                for (int qq = 0; qq < 8; ++qq){
                    int s = __builtin_amdgcn_readlane(myidx, q0 + qq);
                    vv[qq] = bfs(xlt[(unsigned)(s * 64) + lane]);
                }
                #pragma unroll
                for (int qq = 0; qq < 8; ++qq){
                    float wq = __uint_as_float(
                        __builtin_amdgcn_readlane(__float_as_uint(wmine), q0 + qq));
                    acc += wq * vv[qq];
                }
            }
        }
        hv = elu1(acc / denom + b2[lane]);
    }
    __shared__ float red[4][64];
    __shared__ int gid[4];
    red[w][lane] = hv;
    if (lane == 0) gid[w] = g;
    __syncthreads();
    if (w == 0){
        int g0 = gid[0], g1 = gid[1], g2 = gid[2], g3 = gid[3];
        float* pb = pooled + (size_t)br * 4096;
        if (g0 >= 0 && g0 == g1 && g1 == g2 && g2 == g3){
            float s = (red[0][lane] + red[1][lane]) + (red[2][lane] + red[3][lane]);
            atomicAdd(&pb[g0 * 64 + lane], s);
        } else {
            #pragma unroll
            for (int q = 0; q < 4; ++q)
                if (gid[q] >= 0) atomicAdd(&pb[gid[q] * 64 + lane], red[q][lane]);
        }
    }
}

// counts (binary search on sorted batch) + branch MLPs + combine + final head
__global__ __launch_bounds__(1024) void tail_kernel(
    const float* __restrict__ pooled,
    const int* __restrict__ batchb, const int* __restrict__ batcht,
    const float* __restrict__ M1wb, const float* __restrict__ M1bb,
    const float* __restrict__ M2wb, const float* __restrict__ M2bb,
    const float* __restrict__ M1wt, const float* __restrict__ M1bt,
    const float* __restrict__ M2wt, const float* __restrict__ M2bt,
    const float* __restrict__ Fw1, const float* __restrict__ Fb1,
    const float* __restrict__ Fw2, const float* __restrict__ Fb2,
    float* __restrict__ out, int N){
    __shared__ float P[8192];
    __shared__ float H[8192];
    __shared__ float cl[128];
    int t = threadIdx.x;
    if (t < 128){
        int br = t >> 6, g = t & 63;
        const int* batch = br ? batcht : batchb;
        int lo = 0, hi = N;
        while (lo < hi){ int mid = (lo + hi) >> 1; if (batch[mid] < g) lo = mid + 1; else hi = mid; }
        int beg = lo;
        hi = N;
        while (lo < hi){ int mid = (lo + hi) >> 1; if (batch[mid] < g + 1) lo = mid + 1; else hi = mid; }
        cl[t] = (float)(lo - beg);
    }
    __syncthreads();
    for (int i = t; i < 8192; i += 1024)
        P[i] = pooled[i] / fmaxf(cl[i >> 6], 1.f);
    __syncthreads();
    for (int i = t; i < 8192; i += 1024){
        int br = i >> 12, r = (i >> 6) & 63, c = i & 63;
        const float* M1w = br ? M1wt : M1wb;
        const float* M1b = br ? M1bt : M1bb;
        float acc = M1b[c];
        int pb = (br << 12) + (r << 6);
        #pragma unroll 8
        for (int k = 0; k < 64; ++k) acc += P[pb + k] * M1w[(k << 6) + c];
        H[i] = fmaxf(acc, 0.f);
    }
    __syncthreads();
    for (int i = t; i < 8192; i += 1024){
        int br = i >> 12, r = (i >> 6) & 63, c = i & 63;
        const float* M2w = br ? M2wt : M2wb;
        const float* M2b = br ? M2bt : M2bb;
        float acc = M2b[c];
        int hb = (br << 12) + (r << 6);
        #pragma unroll 8
        for (int k = 0; k < 64; ++k) acc += H[hb + k] * M2w[(k << 6) + c];
        P[i] = acc;
    }
    __syncthreads();
    for (int i = t; i < 4096; i += 1024) H[i] = P[i] * P[4096 + i];
    __syncthreads();
    for (int i = t; i < 4096; i += 1024){
        int r = i >> 6, c = i & 63;
        float acc = Fb1[c];
        #pragma unroll 8
        for (int k = 0; k < 64; ++k) acc += H[(r << 6) + k] * Fw1[(k << 6) + c];
        P[i] = fmaxf(acc, 0.f);
    }
    __syncthreads();
    if (t < 128){
        int r = t >> 1, jc = t & 1;
        float acc = Fb2[jc];
        #pragma unroll 8
        for (int k = 0; k < 64; ++k) acc += P[(r << 6) + k] * Fw2[k * 2 + jc];
        out[t] = tanhf(acc);
    }
}

extern "C" void kernel_launch(void* const* d_in, const int* in_sizes, int n_in,
                              void* d_out, int out_size, void* d_ws, size_t ws_size,
                              hipStream_t stream){
    const int N = in_sizes[0] / 2;
    const int E = in_sizes[1] / 2;
    const int NB = (N + 511) >> BSH;   // nodes-per-bucket = 512, NB <= 128

    char* ws = (char*)d_ws;
    size_t off = 0;
    auto alloc = [&](size_t bytes) -> char* {
        char* p = ws + off;
        off += (bytes + 255) & ~(size_t)255;
        return p;
    };
    unsigned short* XL2h = (unsigned short*)alloc((size_t)2 * N * 64 * 2);  // EPAIR aliases this
    float* ES2 = (float*)alloc((size_t)2 * N * 4);
    float* ED2 = (float*)alloc((size_t)2 * N * 4);
    int* RS  = (int*)alloc((size_t)2 * (N + 1) * 4);
    int* CSR = (int*)alloc((size_t)2 * E * 4);
    int* BCUR = (int*)alloc((size_t)2 * NB * 4);
    float* POOLED = (float*)alloc(8192 * 4);
    unsigned short* W2T = (unsigned short*)alloc(2 * 8192 * 2);
    float* ALPH = (float*)alloc(16 * 4);
    unsigned* EPAIR = (unsigned*)XL2h;   // 2*NB*ARENA*4 <= 2*N*128 bytes; dead after csr

    const float* xb   = (const float*)d_in[0];
    const int*   eib  = (const int*)  d_in[1];
    const int*   batchb = (const int*)d_in[2];
    const float* W1b  = (const float*)d_in[3];
    const float* a1sb = (const float*)d_in[4];
    const float* a1db = (const float*)d_in[5];
    const float* b1b  = (const float*)d_in[6];
    const float* W2b  = (const float*)d_in[7];
    const float* a2sb = (const float*)d_in[8];
    const float* a2db = (const float*)d_in[9];
    const float* b2b  = (const float*)d_in[10];
    const float* M1wb = (const float*)d_in[11];
    const float* M1bb = (const float*)d_in[12];
    const float* M2wb = (const float*)d_in[13];
    const float* M2bb = (const float*)d_in[14];
    const float* xt   = (const float*)d_in[15];
    const int*   eit  = (const int*)  d_in[16];
    const int*   batcht = (const int*)d_in[17];
    const float* W1t  = (const float*)d_in[18];
    const float* a1st = (const float*)d_in[19];
    const float* a1dt = (const float*)d_in[20];
    const float* b1t  = (const float*)d_in[21];
    const float* W2t  = (const float*)d_in[22];
    const float* a2st = (const float*)d_in[23];
    const float* a2dt = (const float*)d_in[24];
    const float* b2t  = (const float*)d_in[25];
    const float* M1wt = (const float*)d_in[26];
    const float* M1bt = (const float*)d_in[27];
    const float* M2wt = (const float*)d_in[28];
    const float* M2bt = (const float*)d_in[29];
    const float* Fw1  = (const float*)d_in[30];
    const float* Fb1  = (const float*)d_in[31];
    const float* Fw2  = (const float*)d_in[32];
    const float* Fb2  = (const float*)d_in[33];

    const int nodeBlocks = (N + 3) / 4;
    const int histBlocks = (E + BINCH - 1) / BINCH;
    const int tilesPer   = (N + 31) / 32;

    hipMemsetAsync(BCUR, 0, (size_t)2 * NB * 4, stream);
    preb_kernel<<<2 * histBlocks + 3, 256, 0, stream>>>(
        W1b, W1t, a1sb, a1st, a1db, a1dt, eib, eit, W2b, W2t,
        BCUR, EPAIR, W2T, ALPH, POOLED, N, E, NB, histBlocks);
    csr_kernel<<<2 * NB, 1024, 0, stream>>>(BCUR, EPAIR, RS, CSR, N, E, NB);
    a1f2_kernel<<<2 * tilesPer, 256, 0, stream>>>(
        xb, xt, ALPH, CSR, RS, W1b, W1t, b1b, b1t, W2T,
        a2sb, a2st, a2db, a2dt, XL2h, ES2, ED2, N, E);
    a2pl_kernel<<<2 * nodeBlocks, 256, 0, stream>>>(
        XL2h, ES2, ED2, CSR, RS, b2b, b2t, batchb, batcht, POOLED, N, E);
    tail_kernel<<<1, 1024, 0, stream>>>(POOLED, batchb, batcht,
        M1wb, M1bb, M2wb, M2bb, M1wt, M1bt, M2wt, M2bt,
        Fw1, Fb1, Fw2, Fb2, (float*)d_out, N);
}